// Round 13
// baseline (217.291 us; speedup 1.0000x reference)
//
#include <hip/hip_runtime.h>
#include <hip/hip_bf16.h>
#include <cstdint>
#include <math.h>

#define BB 256
#define CC 64
#define TT 4000
#define NHID 64
#define NOUT 64
#define NMLP (NOUT*(CC+1))  // 4160
#define TCH 128             // t per apply sub-chunk

typedef __attribute__((ext_vector_type(8))) short short8v;  // 8 bf16 = 4 VGPR
typedef __attribute__((ext_vector_type(4))) float f32x4;    // MFMA C/D frag

// ---------------- fully fused: variance -> MLP -> MFMA apply ----------------
// grid 256 (one block per sample b), block 1024 (16 waves, 1 block/CU).
// Phase 1: per-channel log-variance (16 threads/row).
// Phase 2: MLP; W -> LDS bf16 swizzled [o][c], bias -> LDS fp32.
// Phase 3: 4 sub-blocks x 8 iterations of the R12 MFMA body:
//   stage x -> bf16 hi/lo split -> LDS [t][c] (XOR swizzle) -> 32 MFMA ->
//   LDS transpose -> full-line f32x4 non-temporal stores.
__global__ __launch_bounds__(1024) void k_fused(const float* __restrict__ x,
                                                const float* __restrict__ W1,
                                                const float* __restrict__ b1,
                                                const float* __restrict__ W2,
                                                const float* __restrict__ b2,
                                                float* __restrict__ out) {
    int b   = blockIdx.x;
    int tid = threadIdx.x;

    __shared__ unsigned short xt[4][2][TCH * CC];  // 4 sub-blocks x {hi,lo} = 128 KB
    __shared__ unsigned short wl[4096];            // 8 KB, swizzled [o][c] bf16
    __shared__ float bl[64];
    __shared__ float fs[CC];
    __shared__ float hs[NHID];

    // ---------- phase 1: per-channel log-variance over T ----------
    {
        int c   = tid >> 4;      // 0..63
        int sub = tid & 15;      // 0..15
        const float4* row = (const float4*)(x + (size_t)b * (CC * TT) + (size_t)c * TT);
        float s = 0.f, ss = 0.f;
        #pragma unroll 4
        for (int i = sub; i < TT / 4; i += 16) {
            float4 v = row[i];
            s  += v.x + v.y + v.z + v.w;
            ss += v.x * v.x + v.y * v.y + v.z * v.z + v.w * v.w;
        }
        #pragma unroll
        for (int off = 8; off > 0; off >>= 1) {
            s  += __shfl_xor(s, off);
            ss += __shfl_xor(ss, off);
        }
        if (sub == 0) {
            float var = (ss - s * s / (float)TT) / (float)(TT - 1);
            float f = logf(var);
            if (isinf(f) && f < 0.f) f = 0.f;   // jnp.where(isneginf, 0, .)
            fs[c] = f;
        }
    }
    __syncthreads();

    // ---------- phase 2: MLP hypernetwork ----------
    if (tid < NHID) {
        float v = b1[tid];
        #pragma unroll 8
        for (int k = 0; k < CC; ++k) v = fmaf(fs[k], W1[k * NHID + tid], v);
        hs[tid] = v > 0.f ? v : 0.f;
    }
    __syncthreads();
    for (int j = tid; j < NMLP; j += 1024) {
        float v = b2[j];
        #pragma unroll 8
        for (int k = 0; k < NHID; ++k) v = fmaf(hs[k], W2[k * NMLP + j], v);
        if (j < NOUT) {
            bl[j] = v;
        } else {
            int o = (j - NOUT) >> 6, c = (j - NOUT) & 63;   // mlp_out[64+o*64+c]=W[o][c]
            __hip_bfloat16 h = __float2bfloat16(v);
            int byte = o * 128 + ((2 * c) ^ ((o & 7) << 4));  // swizzled store
            *(unsigned short*)((char*)wl + byte) = *(unsigned short*)&h;
        }
    }
    __syncthreads();

    // ---------- phase 3: apply ----------
    int sb    = tid >> 8;        // sub-block 0..3 (4 consecutive waves)
    int stid  = tid & 255;
    int l     = stid & 63;       // lane
    int w     = stid >> 6;       // wave within sub-block 0..3
    int cslot = stid & 7;        // staging: c-octet
    int f4    = stid >> 3;       // staging: t-quad 0..31

    // A-fragments (W) + bias, loaded once (wl/bl constant all iterations)
    short8v af[4][2];
    #pragma unroll
    for (int mi = 0; mi < 4; ++mi)
        #pragma unroll
        for (int kc = 0; kc < 2; ++kc) {
            int o = mi * 16 + (l & 15);
            int colbyte = kc * 64 + (l >> 4) * 16;
            af[mi][kc] = *(const short8v*)((const char*)wl
                             + o * 128 + (colbyte ^ ((o & 7) << 4)));
        }
    float4 bvr[4];
    #pragma unroll
    for (int mi = 0; mi < 4; ++mi)
        bvr[mi] = *(const float4*)&bl[mi * 16 + (l >> 4) * 4];

    unsigned short* xts = &xt[sb][0][0];   // hi plane
    unsigned short* xtl = &xt[sb][1][0];   // lo plane
    float*          ot  = (float*)&xt[sb][0][0];  // 64x128 fp32 transpose buf (reuse)

    #pragma unroll 1
    for (int it = 0; it < 8; ++it) {
        int tb = (it * 4 + sb) * TCH;      // chunks 0..31 cover t = 0..4095

        // ---- stage x chunk -> bf16 hi/lo -> swizzled LDS [t][c] ----
        int maxf4 = ((TT - tb) >> 2) - 1;  // 7 on the tail chunk only
        int f4c   = f4 <= maxf4 ? f4 : maxf4;
        const float* xb = x + (size_t)b * (CC * TT) + tb + f4c * 4;
        float4 xr[8];
        #pragma unroll
        for (int p = 0; p < 8; ++p)
            xr[p] = *(const float4*)(xb + (size_t)(cslot * 8 + p) * TT);
        #pragma unroll
        for (int j = 0; j < 4; ++j) {
            int t = f4 * 4 + j;
            short8v hv, lv;
            #pragma unroll
            for (int p = 0; p < 8; ++p) {
                float v = (&xr[p].x)[j];
                __hip_bfloat16 h = __float2bfloat16(v);              // RTN hi
                unsigned short hu = *(unsigned short*)&h;
                float hf = __uint_as_float((unsigned)hu << 16);
                __hip_bfloat16 lo2 = __float2bfloat16(v - hf);       // RTN residual
                hv[p] = (short)hu;
                lv[p] = (short)*(unsigned short*)&lo2;
            }
            int byteoff = t * 128 + ((cslot * 16) ^ ((t & 7) << 4)); // XOR swizzle
            *(short8v*)((char*)xts + byteoff) = hv;
            *(short8v*)((char*)xtl + byteoff) = lv;
        }
        __syncthreads();                   // (1) staging visible

        // ---- MFMA: 2 t-tiles x 4 o-tiles x (2 kc x hi/lo) ----
        f32x4 acc[4][2];
        #pragma unroll
        for (int mi = 0; mi < 4; ++mi)
            #pragma unroll
            for (int ti = 0; ti < 2; ++ti) {
                acc[mi][ti][0] = bvr[mi].x; acc[mi][ti][1] = bvr[mi].y;
                acc[mi][ti][2] = bvr[mi].z; acc[mi][ti][3] = bvr[mi].w;
            }
        #pragma unroll
        for (int ti = 0; ti < 2; ++ti) {
            int tl = w * 32 + ti * 16 + (l & 15);
            int rowbase = tl * 128;
            int sw = (tl & 7) << 4;
            short8v bf[2][2];
            #pragma unroll
            for (int kc = 0; kc < 2; ++kc) {
                int boff = rowbase + ((kc * 64 + (l >> 4) * 16) ^ sw);
                bf[kc][0] = *(const short8v*)((const char*)xts + boff);
                bf[kc][1] = *(const short8v*)((const char*)xtl + boff);
            }
            #pragma unroll
            for (int mi = 0; mi < 4; ++mi)
                #pragma unroll
                for (int kc = 0; kc < 2; ++kc) {
                    acc[mi][ti] = __builtin_amdgcn_mfma_f32_16x16x32_bf16(
                                      af[mi][kc], bf[kc][0], acc[mi][ti], 0, 0, 0);
                    acc[mi][ti] = __builtin_amdgcn_mfma_f32_16x16x32_bf16(
                                      af[mi][kc], bf[kc][1], acc[mi][ti], 0, 0, 0);
                }
        }
        __syncthreads();                   // (2) all xt reads done -> reuse as ot

        // ---- transpose via LDS ----
        #pragma unroll
        for (int mi = 0; mi < 4; ++mi)
            #pragma unroll
            for (int ti = 0; ti < 2; ++ti) {
                int t = w * 32 + ti * 16 + (l & 15);
                #pragma unroll
                for (int r = 0; r < 4; ++r) {
                    int o = mi * 16 + (l >> 4) * 4 + r;
                    ot[o * 128 + (t ^ ((o & 7) << 2))] = acc[mi][ti][r];
                }
            }
        __syncthreads();                   // (3) transpose written

        // ---- full-line f32x4 non-temporal stores ----
        int ro = stid >> 3;                // o-row 0..31 (two passes)
        int q0 = stid & 7;
        #pragma unroll
        for (int k2 = 0; k2 < 2; ++k2) {
            int o = ro + k2 * 32;
            int sw2 = (o & 7) << 2;
            float* op = out + (size_t)b * (NOUT * TT) + (size_t)o * TT + tb;
            #pragma unroll
            for (int kq = 0; kq < 4; ++kq) {
                int t0 = (q0 + kq * 8) * 4;
                if (tb + t0 < TT) {
                    f32x4 v = *(const f32x4*)&ot[o * 128 + (t0 ^ sw2)];
                    __builtin_nontemporal_store(v, (f32x4*)(op + t0));
                }
            }
        }
        __syncthreads();                   // (4) store reads done before next staging
    }
}

extern "C" void kernel_launch(void* const* d_in, const int* in_sizes, int n_in,
                              void* d_out, int out_size, void* d_ws, size_t ws_size,
                              hipStream_t stream) {
    const float* x  = (const float*)d_in[0];
    const float* W1 = (const float*)d_in[1];
    const float* b1 = (const float*)d_in[2];
    const float* W2 = (const float*)d_in[3];
    const float* b2 = (const float*)d_in[4];
    float* out = (float*)d_out;

    k_fused<<<256, 1024, 0, stream>>>(x, W1, b1, W2, b2, out);
}

// Round 14
// 214.237 us; speedup vs baseline: 1.0143x; 1.0143x over previous
//
#include <hip/hip_runtime.h>
#include <hip/hip_bf16.h>
#include <cstdint>
#include <math.h>

#define BB 256
#define CC 64
#define TT 4000
#define NHID 64
#define NOUT 64
#define NMLP (NOUT*(CC+1))  // 4160
#define TCH 128             // t per apply sub-chunk

typedef __attribute__((ext_vector_type(8))) short short8v;  // 8 bf16 = 4 VGPR
typedef __attribute__((ext_vector_type(4))) float f32x4;    // MFMA C/D frag

// ---------------- fully fused: variance -> MLP -> MFMA apply ----------------
// grid 256 (one block per sample b), block 1024 (16 waves, 1 block/CU).
// __launch_bounds__(1024, 4): 4 waves/EU = our exact occupancy -> VGPR cap 128
// (R13 bug: default allocation chose 64 VGPR for a ~110-VGPR working set -> spills).
__global__ __launch_bounds__(1024, 4) void k_fused(const float* __restrict__ x,
                                                   const float* __restrict__ W1,
                                                   const float* __restrict__ b1,
                                                   const float* __restrict__ W2,
                                                   const float* __restrict__ b2,
                                                   float* __restrict__ out) {
    int b   = blockIdx.x;
    int tid = threadIdx.x;

    __shared__ unsigned short xt[4][2][TCH * CC];  // 4 sub-blocks x {hi,lo} = 128 KB
    __shared__ unsigned short wl[4096];            // 8 KB, swizzled [o][c] bf16
    __shared__ float bl[64];
    __shared__ float fs[CC];
    __shared__ float hs[NHID];

    // ---------- phase 1: per-channel log-variance over T ----------
    {
        int c   = tid >> 4;      // 0..63
        int sub = tid & 15;      // 0..15
        const float4* row = (const float4*)(x + (size_t)b * (CC * TT) + (size_t)c * TT);
        float s = 0.f, ss = 0.f;
        #pragma unroll 4
        for (int i = sub; i < TT / 4; i += 16) {
            float4 v = row[i];
            s  += v.x + v.y + v.z + v.w;
            ss += v.x * v.x + v.y * v.y + v.z * v.z + v.w * v.w;
        }
        #pragma unroll
        for (int off = 8; off > 0; off >>= 1) {
            s  += __shfl_xor(s, off);
            ss += __shfl_xor(ss, off);
        }
        if (sub == 0) {
            float var = (ss - s * s / (float)TT) / (float)(TT - 1);
            float f = logf(var);
            if (isinf(f) && f < 0.f) f = 0.f;   // jnp.where(isneginf, 0, .)
            fs[c] = f;
        }
    }
    __syncthreads();

    // ---------- phase 2: MLP hypernetwork ----------
    if (tid < NHID) {
        float v = b1[tid];
        #pragma unroll 8
        for (int k = 0; k < CC; ++k) v = fmaf(fs[k], W1[k * NHID + tid], v);
        hs[tid] = v > 0.f ? v : 0.f;
    }
    __syncthreads();
    for (int j = tid; j < NMLP; j += 1024) {
        float v = b2[j];
        #pragma unroll 8
        for (int k = 0; k < NHID; ++k) v = fmaf(hs[k], W2[k * NMLP + j], v);
        if (j < NOUT) {
            bl[j] = v;
        } else {
            int o = (j - NOUT) >> 6, c = (j - NOUT) & 63;   // mlp_out[64+o*64+c]=W[o][c]
            __hip_bfloat16 h = __float2bfloat16(v);
            int byte = o * 128 + ((2 * c) ^ ((o & 7) << 4));  // swizzled store
            *(unsigned short*)((char*)wl + byte) = *(unsigned short*)&h;
        }
    }
    __syncthreads();

    // ---------- phase 3: apply ----------
    int sb    = tid >> 8;        // sub-block 0..3 (4 consecutive waves)
    int stid  = tid & 255;
    int l     = stid & 63;       // lane
    int w     = stid >> 6;       // wave within sub-block 0..3
    int cslot = stid & 7;        // staging: c-octet
    int f4    = stid >> 3;       // staging: t-quad 0..31

    // A-fragments (W) + bias, loaded once (wl/bl constant all iterations)
    short8v af[4][2];
    #pragma unroll
    for (int mi = 0; mi < 4; ++mi)
        #pragma unroll
        for (int kc = 0; kc < 2; ++kc) {
            int o = mi * 16 + (l & 15);
            int colbyte = kc * 64 + (l >> 4) * 16;
            af[mi][kc] = *(const short8v*)((const char*)wl
                             + o * 128 + (colbyte ^ ((o & 7) << 4)));
        }
    float4 bvr[4];
    #pragma unroll
    for (int mi = 0; mi < 4; ++mi)
        bvr[mi] = *(const float4*)&bl[mi * 16 + (l >> 4) * 4];

    unsigned short* xts = &xt[sb][0][0];   // hi plane
    unsigned short* xtl = &xt[sb][1][0];   // lo plane
    float*          ot  = (float*)&xt[sb][0][0];  // 64x128 fp32 transpose buf (reuse)

    #pragma unroll 1
    for (int it = 0; it < 8; ++it) {
        int tb = (it * 4 + sb) * TCH;      // chunks 0..31 cover t = 0..4095

        // ---- stage x chunk -> bf16 hi/lo -> swizzled LDS [t][c] ----
        int maxf4 = ((TT - tb) >> 2) - 1;  // 7 on the tail chunk only
        int f4c   = f4 <= maxf4 ? f4 : maxf4;
        const float* xb = x + (size_t)b * (CC * TT) + tb + f4c * 4;
        float4 xr[8];
        #pragma unroll
        for (int p = 0; p < 8; ++p)
            xr[p] = *(const float4*)(xb + (size_t)(cslot * 8 + p) * TT);
        #pragma unroll
        for (int j = 0; j < 4; ++j) {
            int t = f4 * 4 + j;
            short8v hv, lv;
            #pragma unroll
            for (int p = 0; p < 8; ++p) {
                float v = (&xr[p].x)[j];
                __hip_bfloat16 h = __float2bfloat16(v);              // RTN hi
                unsigned short hu = *(unsigned short*)&h;
                float hf = __uint_as_float((unsigned)hu << 16);
                __hip_bfloat16 lo2 = __float2bfloat16(v - hf);       // RTN residual
                hv[p] = (short)hu;
                lv[p] = (short)*(unsigned short*)&lo2;
            }
            int byteoff = t * 128 + ((cslot * 16) ^ ((t & 7) << 4)); // XOR swizzle
            *(short8v*)((char*)xts + byteoff) = hv;
            *(short8v*)((char*)xtl + byteoff) = lv;
        }
        __syncthreads();                   // (1) staging visible

        // ---- MFMA: 2 t-tiles x 4 o-tiles x (2 kc x hi/lo) ----
        f32x4 acc[4][2];
        #pragma unroll
        for (int mi = 0; mi < 4; ++mi)
            #pragma unroll
            for (int ti = 0; ti < 2; ++ti) {
                acc[mi][ti][0] = bvr[mi].x; acc[mi][ti][1] = bvr[mi].y;
                acc[mi][ti][2] = bvr[mi].z; acc[mi][ti][3] = bvr[mi].w;
            }
        #pragma unroll
        for (int ti = 0; ti < 2; ++ti) {
            int tl = w * 32 + ti * 16 + (l & 15);
            int rowbase = tl * 128;
            int sw = (tl & 7) << 4;
            short8v bf[2][2];
            #pragma unroll
            for (int kc = 0; kc < 2; ++kc) {
                int boff = rowbase + ((kc * 64 + (l >> 4) * 16) ^ sw);
                bf[kc][0] = *(const short8v*)((const char*)xts + boff);
                bf[kc][1] = *(const short8v*)((const char*)xtl + boff);
            }
            #pragma unroll
            for (int mi = 0; mi < 4; ++mi)
                #pragma unroll
                for (int kc = 0; kc < 2; ++kc) {
                    acc[mi][ti] = __builtin_amdgcn_mfma_f32_16x16x32_bf16(
                                      af[mi][kc], bf[kc][0], acc[mi][ti], 0, 0, 0);
                    acc[mi][ti] = __builtin_amdgcn_mfma_f32_16x16x32_bf16(
                                      af[mi][kc], bf[kc][1], acc[mi][ti], 0, 0, 0);
                }
        }
        __syncthreads();                   // (2) all xt reads done -> reuse as ot

        // ---- transpose via LDS ----
        #pragma unroll
        for (int mi = 0; mi < 4; ++mi)
            #pragma unroll
            for (int ti = 0; ti < 2; ++ti) {
                int t = w * 32 + ti * 16 + (l & 15);
                #pragma unroll
                for (int r = 0; r < 4; ++r) {
                    int o = mi * 16 + (l >> 4) * 4 + r;
                    ot[o * 128 + (t ^ ((o & 7) << 2))] = acc[mi][ti][r];
                }
            }
        __syncthreads();                   // (3) transpose written

        // ---- full-line f32x4 non-temporal stores ----
        int ro = stid >> 3;                // o-row 0..31 (two passes)
        int q0 = stid & 7;
        #pragma unroll
        for (int k2 = 0; k2 < 2; ++k2) {
            int o = ro + k2 * 32;
            int sw2 = (o & 7) << 2;
            float* op = out + (size_t)b * (NOUT * TT) + (size_t)o * TT + tb;
            #pragma unroll
            for (int kq = 0; kq < 4; ++kq) {
                int t0 = (q0 + kq * 8) * 4;
                if (tb + t0 < TT) {
                    f32x4 v = *(const f32x4*)&ot[o * 128 + (t0 ^ sw2)];
                    __builtin_nontemporal_store(v, (f32x4*)(op + t0));
                }
            }
        }
        __syncthreads();                   // (4) store reads done before next staging
    }
}

extern "C" void kernel_launch(void* const* d_in, const int* in_sizes, int n_in,
                              void* d_out, int out_size, void* d_ws, size_t ws_size,
                              hipStream_t stream) {
    const float* x  = (const float*)d_in[0];
    const float* W1 = (const float*)d_in[1];
    const float* b1 = (const float*)d_in[2];
    const float* W2 = (const float*)d_in[3];
    const float* b2 = (const float*)d_in[4];
    float* out = (float*)d_out;

    k_fused<<<256, 1024, 0, stream>>>(x, W1, b1, W2, b2, out);
}

// Round 16
// 147.932 us; speedup vs baseline: 1.4689x; 1.4482x over previous
//
#include <hip/hip_runtime.h>
#include <hip/hip_bf16.h>
#include <cstdint>
#include <math.h>

#define BB 256
#define CC 64
#define TT 4000
#define NHID 64
#define NOUT 64
#define NMLP (NOUT*(CC+1))  // 4160
#define TCH 128             // t per k_apply block

typedef __attribute__((ext_vector_type(8))) short short8v;      // 8 fp16 = 4 VGPR
typedef __attribute__((ext_vector_type(4))) float f32x4;        // MFMA C/D frag
typedef __attribute__((ext_vector_type(2))) __fp16 half2v;      // cvt_pkrtz result

// ---------------- K1: fused per-channel log-variance + MLP hypernetwork ----------------
// grid 256 (one block per sample b), block 1024. 16 threads per channel row.
// Produces wsB[b][o] (fp32) and wtg[b][o][c] (fp16, natural layout for A-frags).
__global__ __launch_bounds__(1024) void k_feat(const float* __restrict__ x,
                                               const float* __restrict__ W1,
                                               const float* __restrict__ b1,
                                               const float* __restrict__ W2,
                                               const float* __restrict__ b2,
                                               unsigned short* __restrict__ wtg,
                                               float* __restrict__ wsB) {
    int b   = blockIdx.x;
    int tid = threadIdx.x;
    int c   = tid >> 4;      // 0..63
    int sub = tid & 15;      // 0..15

    const float4* row = (const float4*)(x + (size_t)b * (CC * TT) + (size_t)c * TT);
    float s = 0.f, ss = 0.f;
    #pragma unroll 4
    for (int i = sub; i < TT / 4; i += 16) {   // 1000 float4 per row / 16 threads
        float4 v = row[i];
        s  += v.x + v.y + v.z + v.w;
        ss += v.x * v.x + v.y * v.y + v.z * v.z + v.w * v.w;
    }
    #pragma unroll
    for (int off = 8; off > 0; off >>= 1) {
        s  += __shfl_xor(s, off);
        ss += __shfl_xor(ss, off);
    }

    __shared__ float fs[CC];
    __shared__ float hs[NHID];
    if (sub == 0) {
        float var = (ss - s * s / (float)TT) / (float)(TT - 1);
        float f = logf(var);
        if (isinf(f) && f < 0.f) f = 0.f;   // jnp.where(isneginf, 0, .)
        fs[c] = f;
    }
    __syncthreads();

    if (tid < NHID) {
        float v = b1[tid];
        #pragma unroll 8
        for (int k = 0; k < CC; ++k) v = fmaf(fs[k], W1[k * NHID + tid], v);
        hs[tid] = v > 0.f ? v : 0.f;
    }
    __syncthreads();

    for (int j = tid; j < NMLP; j += 1024) {
        float v = b2[j];
        #pragma unroll 8
        for (int k = 0; k < NHID; ++k) v = fmaf(hs[k], W2[k * NMLP + j], v);
        if (j < NOUT) {
            wsB[b * NOUT + j] = v;
        } else {
            // mlp_out[64 + o*64 + c] = W[o][c] -> natural [o][c] fp16 (RTN)
            _Float16 hf = (_Float16)v;
            wtg[(size_t)b * 4096 + (j - NOUT)] = *(unsigned short*)&hf;
        }
    }
}

// ---------------- K2 (MFMA fp16): out[b,o,t] = sum_c W[o,c]*x[b,c,t] + bias[o] ----------------
// grid (32, 256), block 256 (4 waves). Stage x fp32 -> fp16 (v_cvt_pkrtz) ->
// LDS [t][c] single plane (16 KB, XOR swizzle). 16 mfma_f32_16x16x32_f16/wave.
// Epilogue: LDS transpose (same 32 KB buffer) -> full-line f32x4 NT stores.
// LDS 32 KB -> 5 blocks/CU.
__global__ __launch_bounds__(256, 4) void k_apply(const float* __restrict__ x,
                                                  const unsigned short* __restrict__ wtg,
                                                  const float* __restrict__ wsB,
                                                  float* __restrict__ out) {
    int b   = (BB - 1) - blockIdx.y;    // reversed: reuse x tail from k_feat in L3
    int tb  = blockIdx.x * TCH;
    int tid = threadIdx.x;
    int l   = tid & 63, w = tid >> 6;

    __shared__ __align__(16) char ldsb[TCH * CC * 4];     // 32 KB
    float* ot = (float*)ldsb;                             // epilogue: 64x128 fp32

    // ---- staging: thread owns c-octet (cslot) x t-quad (f4) ----
    int cslot = tid & 7;                 // c = cslot*8 + p
    int f4    = tid >> 3;                // t-quad 0..31
    int maxf4 = ((TT - tb) >> 2) - 1;    // 7 on tail chunk only
    int f4c   = f4 <= maxf4 ? f4 : maxf4;
    const float* xb = x + (size_t)b * (CC * TT) + tb + f4c * 4;

    float4 xr[8];
    #pragma unroll
    for (int p = 0; p < 8; ++p)
        xr[p] = *(const float4*)(xb + (size_t)(cslot * 8 + p) * TT);

    // convert each row-quad to 4 packed fp16 (RTZ; err 2^-11 rel, fine vs thr)
    uint2 h4[8];
    #pragma unroll
    for (int p = 0; p < 8; ++p) {
        half2v p0 = __builtin_amdgcn_cvt_pkrtz(xr[p].x, xr[p].y);
        half2v p1 = __builtin_amdgcn_cvt_pkrtz(xr[p].z, xr[p].w);
        h4[p].x = *(unsigned*)&p0;
        h4[p].y = *(unsigned*)&p1;
    }
    #pragma unroll
    for (int j = 0; j < 4; ++j) {
        int t = f4 * 4 + j;
        short8v hv;
        #pragma unroll
        for (int p = 0; p < 8; ++p) {
            unsigned word = (j < 2) ? h4[p].x : h4[p].y;
            hv[p] = (short)((j & 1) ? (word >> 16) : (word & 0xFFFFu));
        }
        int byteoff = t * 128 + ((cslot * 16) ^ ((t & 7) << 4));    // XOR swizzle
        *(short8v*)(ldsb + byteoff) = hv;
    }
    __syncthreads();

    // ---- A-fragments (W fp16) straight from global (L2-hot; 16B/lane) ----
    const unsigned short* wb = wtg + (size_t)b * 4096;
    short8v af[4][2];
    #pragma unroll
    for (int mi = 0; mi < 4; ++mi)
        #pragma unroll
        for (int kc = 0; kc < 2; ++kc)
            af[mi][kc] = *(const short8v*)(wb + (mi * 16 + (l & 15)) * 64
                                              + kc * 32 + (l >> 4) * 8);

    // ---- acc init from bias: D row o = (l>>4)*4 + r ----
    f32x4 acc[4][2];
    #pragma unroll
    for (int mi = 0; mi < 4; ++mi) {
        float4 bv = *(const float4*)(wsB + b * 64 + mi * 16 + (l >> 4) * 4);
        #pragma unroll
        for (int ti = 0; ti < 2; ++ti) {
            acc[mi][ti][0] = bv.x; acc[mi][ti][1] = bv.y;
            acc[mi][ti][2] = bv.z; acc[mi][ti][3] = bv.w;
        }
    }

    // ---- MFMA main: per t-tile read 2 B-frags, run 8 MFMAs ----
    #pragma unroll
    for (int ti = 0; ti < 2; ++ti) {
        int tl = w * 32 + ti * 16 + (l & 15);         // t row in LDS
        int rowbase = tl * 128;
        int sw = (tl & 7) << 4;
        short8v bf[2];
        #pragma unroll
        for (int kc = 0; kc < 2; ++kc) {
            int boff = rowbase + ((kc * 64 + (l >> 4) * 16) ^ sw);
            bf[kc] = *(const short8v*)(ldsb + boff);
        }
        #pragma unroll
        for (int mi = 0; mi < 4; ++mi)
            #pragma unroll
            for (int kc = 0; kc < 2; ++kc)
                acc[mi][ti] = __builtin_amdgcn_mfma_f32_16x16x32_f16(
                                  af[mi][kc], bf[kc], acc[mi][ti], 0, 0, 0);
    }

    // ---- epilogue: transpose via LDS (reuse buffer) then full-line NT stores ----
    __syncthreads();                     // all B-frag reads done; buffer reusable

    #pragma unroll
    for (int mi = 0; mi < 4; ++mi)
        #pragma unroll
        for (int ti = 0; ti < 2; ++ti) {
            int t = w * 32 + ti * 16 + (l & 15);
            #pragma unroll
            for (int r = 0; r < 4; ++r) {
                int o = mi * 16 + (l >> 4) * 4 + r;
                ot[o * 128 + (t ^ ((o & 7) << 2))] = acc[mi][ti][r];  // 2-way (free)
            }
        }
    __syncthreads();

    // read back row-major, 16B/lane, 8 consecutive lanes per o-row
    // (128B contiguous per row per instr = full line -> NT safe)
    int ro = tid >> 3;                   // 0..31 (two o-passes)
    int q0 = tid & 7;                    // quad slot within row
    #pragma unroll
    for (int k2 = 0; k2 < 2; ++k2) {
        int o = ro + k2 * 32;
        int sw2 = (o & 7) << 2;
        float* op = out + (size_t)b * (NOUT * TT) + (size_t)o * TT + tb;
        #pragma unroll
        for (int kq = 0; kq < 4; ++kq) {
            int t0 = (q0 + kq * 8) * 4;
            if (tb + t0 < TT) {
                f32x4 v = *(const f32x4*)&ot[o * 128 + (t0 ^ sw2)];
                __builtin_nontemporal_store(v, (f32x4*)(op + t0));
            }
        }
    }
}

extern "C" void kernel_launch(void* const* d_in, const int* in_sizes, int n_in,
                              void* d_out, int out_size, void* d_ws, size_t ws_size,
                              hipStream_t stream) {
    const float* x  = (const float*)d_in[0];
    const float* W1 = (const float*)d_in[1];
    const float* b1 = (const float*)d_in[2];
    const float* W2 = (const float*)d_in[3];
    const float* b2 = (const float*)d_in[4];
    float* out = (float*)d_out;
    float* ws  = (float*)d_ws;

    float*          wsB = ws;                               // 256*64 fp32
    unsigned short* wtg = (unsigned short*)(ws + 16384);    // 256*4096 fp16 (2 MB)

    k_feat<<<256, 1024, 0, stream>>>(x, W1, b1, W2, b2, wtg, wsB);
    k_apply<<<dim3(32, 256), 256, 0, stream>>>(x, wtg, wsB, out);
}